// Round 14
// baseline (735.707 us; speedup 1.0000x reference)
//
#include <hip/hip_runtime.h>

#define NN 100000
#define NE 1600000
#define DIM0 11
#define H 128
#define NL 4
#define NG 4096
#define EPS 1e-5f

#define NBKT 391       // buckets of 256 nodes: bucket = dst >> 8
#define CAP 5120       // fixed bucket capacity (mean 4096, sigma 64 -> 16 sigma)
#define EPB 4096       // edges per block in scatter phase
static constexpr int NBB = (NE + EPB - 1) / EPB;  // 391

typedef _Float16 f16x8 __attribute__((ext_vector_type(8)));
typedef _Float16 f16x2 __attribute__((ext_vector_type(2)));
typedef float f32x4 __attribute__((ext_vector_type(4)));

// r13 lesson: static partitions at any block size plateau at ~85us/55% occ.
// The fused gather is LATENCY-bound per node: avg degree 16 = one 4-gather
// batch, then a shfl-combine drain, serialized over 16 nodes/wave. Fix:
// interleave 2 nodes -> 8 gathers in flight, one drain per TWO nodes.

// ---------------- init ----------------

__global__ void k_init(int* __restrict__ bfill, int* __restrict__ gstart, int* __restrict__ gend) {
    int i = blockIdx.x * 256 + threadIdx.x;
    if (i <= NBKT) bfill[i] = 0;
    if (i < NG) { gstart[i] = 0x7fffffff; gend[i] = 0; }
}

// ---------------- bucketed CSR build ----------------

__global__ __launch_bounds__(256) void k_bscatter(const int* __restrict__ src, const int* __restrict__ dst,
                                                  int* __restrict__ bfill, unsigned int* __restrict__ ebuf) {
    __shared__ int lc[NBKT];
    __shared__ int lbase[NBKT];
    int t = threadIdx.x;
    for (int i = t; i < NBKT; i += 256) lc[i] = 0;
    __syncthreads();
    int base = blockIdx.x * EPB;
    int rank[16];
    int bk[16];
    unsigned pk[16];
#pragma unroll
    for (int i = 0; i < 16; i++) {
        int e = base + i * 256 + t;
        if (e < NE) {
            int d = dst[e];
            int s = src[e];
            int b = d >> 8;
            bk[i] = b;
            pk[i] = (unsigned)s | ((unsigned)(d & 255) << 17);
            rank[i] = atomicAdd(&lc[b], 1);
        } else bk[i] = -1;
    }
    __syncthreads();
    for (int i = t; i < NBKT; i += 256)
        lbase[i] = i * CAP + (lc[i] ? atomicAdd(&bfill[i], lc[i]) : 0);
    __syncthreads();
#pragma unroll
    for (int i = 0; i < 16; i++) {
        if (bk[i] >= 0)
            ebuf[lbase[bk[i]] + rank[i]] = pk[i];
    }
}

// One block per bucket (391 blocks): count -> dis, scan -> rps/rpe, scatter -> col.
__global__ __launch_bounds__(256) void k_bcsr(const unsigned int* __restrict__ ebuf,
                                              const int* __restrict__ bfill,
                                              int* __restrict__ rps, int* __restrict__ rpe,
                                              int* __restrict__ col, float* __restrict__ dis) {
    __shared__ int lcnt[256];
    __shared__ int lfill[256];
    __shared__ int tmp[256];
    int t = threadIdx.x;
    int b = blockIdx.x;
    int cb = b * CAP;
    int ecnt = bfill[b];
    int n0 = b << 8;
    int nb = min(256, NN - n0);

    lcnt[t] = 0;
    lfill[t] = 0;
    __syncthreads();

    for (int i = t; i < ecnt; i += 256) {
        unsigned p = ebuf[cb + i];
        atomicAdd(&lcnt[p >> 17], 1);
    }
    __syncthreads();

    if (t < nb) dis[n0 + t] = rsqrtf((float)(lcnt[t] + 1));

    int v = lcnt[t];
    tmp[t] = v;
    __syncthreads();
    for (int off = 1; off < 256; off <<= 1) {
        int x = (t >= off) ? tmp[t - off] : 0;
        __syncthreads();
        tmp[t] += x;
        __syncthreads();
    }
    lcnt[t] = tmp[t] - v;   // exclusive scan
    __syncthreads();

    if (t < nb) {
        rps[n0 + t] = cb + lcnt[t];
        rpe[n0 + t] = cb + ((t < 255) ? lcnt[t + 1] : ecnt);
    }

    for (int i = t; i < ecnt; i += 256) {
        unsigned p = ebuf[cb + i];
        int dl = p >> 17;
        int s = (int)(p & 0x1FFFFu);
        col[cb + lcnt[dl] + atomicAdd(&lfill[dl], 1)] = s;
    }
}

// ---------------- embed: hh = fp16(relu(x @ W_embed + b)), row-major ----------------

__global__ __launch_bounds__(256) void k_embed(const float* __restrict__ x, const float* __restrict__ W,
                                               const float* __restrict__ b, _Float16* __restrict__ hh) {
    __shared__ float Ws[DIM0 * H];
    __shared__ float bs[H];
    __shared__ float xs[16 * DIM0];
    int tid = threadIdx.x;
    for (int i = tid; i < DIM0 * H; i += 256) Ws[i] = W[i];
    if (tid < H) bs[tid] = b[tid];
    if (tid < 16 * DIM0) xs[tid] = x[(size_t)blockIdx.x * (16 * DIM0) + tid];
    __syncthreads();
    int nl = tid >> 4;
    int node = blockIdx.x * 16 + nl;
    int l4 = tid & 15;
    f16x8 o;
#pragma unroll
    for (int j = 0; j < 8; j++) {
        int c = l4 * 8 + j;
        float acc = bs[c];
#pragma unroll
        for (int k = 0; k < DIM0; k++) acc += xs[nl * DIM0 + k] * Ws[k * H + c];
        o[j] = (_Float16)fmaxf(acc, 0.f);
    }
    *(f16x8*)&hh[(size_t)node * H + l4 * 8] = o;
}

// ---------------- W pack: W[l][k][n] fp32 -> B-fragment-layout fp16 ----------------

__global__ __launch_bounds__(256) void k_wpack(const float* __restrict__ W, _Float16* __restrict__ Wp) {
    int t = blockIdx.x * 256 + threadIdx.x;   // 8192 threads
    int lane = t & 63;
    int idx = t >> 6;          // 0..127
    int nt = idx & 7;
    int ks = (idx >> 3) & 3;
    int l = idx >> 5;
    int q = lane >> 4, l15 = lane & 15;
    const float* Wl = W + (size_t)l * H * H;
    _Float16* o = Wp + (size_t)idx * 512 + lane * 8;
#pragma unroll
    for (int j = 0; j < 8; j++)
        o[j] = (_Float16)(Wl[(ks * 32 + q * 8 + j) * H + nt * 16 + l15]);
}

// ---------------- fused layer: hout = relu(LN(agg(hin) @ W + b)) + hin ----------------
// Block = 32 nodes, 2 waves (128 thr); wave-private 4.25KB LDS tile aliased
// between phase-1 agg rows and LN output. Phase 1 interleaves 2 nodes to double
// gather MLP and halve combine-drain frequency. No __syncthreads anywhere.

__global__ __launch_bounds__(128, 6) void k_layer(const _Float16* __restrict__ hin,
                                                  _Float16* __restrict__ hout,
                                                  const float* __restrict__ dis, const int* __restrict__ rps,
                                                  const int* __restrict__ rpe, const int* __restrict__ col,
                                                  const _Float16* __restrict__ Wp,
                                                  const float* __restrict__ bias,
                                                  const float* __restrict__ gamma,
                                                  const float* __restrict__ beta) {
    __shared__ _Float16 Ls[2][16][136];   // 8704 B
    int tid = threadIdx.x;
    int wave = tid >> 6;
    int lane = tid & 63;
    int q = lane >> 4, l4 = lane & 15;
    int nbase = blockIdx.x * 32 + wave * 16;

    const f16x8* h8 = (const f16x8*)hin;

    // ---- phase 1: gather 16 nodes, 2 at a time ----
#pragma unroll 1
    for (int i = 0; i < 16; i += 2) {
        int nA = __builtin_amdgcn_readfirstlane(nbase + i);
        int nB = __builtin_amdgcn_readfirstlane(nbase + i + 1);
        bool vA = nA < NN, vB = nB < NN;
        float aA[8], aB[8];
#pragma unroll
        for (int j = 0; j < 8; j++) { aA[j] = 0.f; aB[j] = 0.f; }

        float dnA = 0.f, dnB = 0.f;
        int eA = 0, e1A = 0, eB = 0, e1B = 0;
        if (vA) { dnA = dis[nA]; eA = rps[nA] + q; e1A = rpe[nA]; }
        if (vB) { dnB = dis[nB]; eB = rps[nB] + q; e1B = rpe[nB]; }

        if (q == 0) {  // self-loops counted once
            if (vA) {
                f16x8 sv = h8[(size_t)nA * 16 + l4];
                float ws = dnA * dnA;
#pragma unroll
                for (int j = 0; j < 8; j++) aA[j] = (float)sv[j] * ws;
            }
            if (vB) {
                f16x8 sv = h8[(size_t)nB * 16 + l4];
                float ws = dnB * dnB;
#pragma unroll
                for (int j = 0; j < 8; j++) aB[j] = (float)sv[j] * ws;
            }
        }

        // joint loop: 8 gathers (8KB) in flight while both nodes have full batches
        while (eA + 12 < e1A && eB + 12 < e1B) {
            int sA0 = col[eA], sA1 = col[eA + 4], sA2 = col[eA + 8], sA3 = col[eA + 12];
            int sB0 = col[eB], sB1 = col[eB + 4], sB2 = col[eB + 8], sB3 = col[eB + 12];
            float wA0 = dis[sA0], wA1 = dis[sA1], wA2 = dis[sA2], wA3 = dis[sA3];
            float wB0 = dis[sB0], wB1 = dis[sB1], wB2 = dis[sB2], wB3 = dis[sB3];
            f16x8 uA0 = h8[(size_t)sA0 * 16 + l4];
            f16x8 uA1 = h8[(size_t)sA1 * 16 + l4];
            f16x8 uA2 = h8[(size_t)sA2 * 16 + l4];
            f16x8 uA3 = h8[(size_t)sA3 * 16 + l4];
            f16x8 uB0 = h8[(size_t)sB0 * 16 + l4];
            f16x8 uB1 = h8[(size_t)sB1 * 16 + l4];
            f16x8 uB2 = h8[(size_t)sB2 * 16 + l4];
            f16x8 uB3 = h8[(size_t)sB3 * 16 + l4];
            wA0 *= dnA; wA1 *= dnA; wA2 *= dnA; wA3 *= dnA;
            wB0 *= dnB; wB1 *= dnB; wB2 *= dnB; wB3 *= dnB;
#pragma unroll
            for (int j = 0; j < 8; j++) {
                aA[j] += (float)uA0[j] * wA0;
                aA[j] += (float)uA1[j] * wA1;
                aA[j] += (float)uA2[j] * wA2;
                aA[j] += (float)uA3[j] * wA3;
                aB[j] += (float)uB0[j] * wB0;
                aB[j] += (float)uB1[j] * wB1;
                aB[j] += (float)uB2[j] * wB2;
                aB[j] += (float)uB3[j] * wB3;
            }
            eA += 16;
            eB += 16;
        }
        // drain A
        for (; eA + 12 < e1A; eA += 16) {
            int s0 = col[eA], s1 = col[eA + 4], s2 = col[eA + 8], s3 = col[eA + 12];
            float w0 = dis[s0], w1 = dis[s1], w2 = dis[s2], w3 = dis[s3];
            f16x8 u0 = h8[(size_t)s0 * 16 + l4];
            f16x8 u1 = h8[(size_t)s1 * 16 + l4];
            f16x8 u2 = h8[(size_t)s2 * 16 + l4];
            f16x8 u3 = h8[(size_t)s3 * 16 + l4];
            w0 *= dnA; w1 *= dnA; w2 *= dnA; w3 *= dnA;
#pragma unroll
            for (int j = 0; j < 8; j++) {
                aA[j] += (float)u0[j] * w0;
                aA[j] += (float)u1[j] * w1;
                aA[j] += (float)u2[j] * w2;
                aA[j] += (float)u3[j] * w3;
            }
        }
        for (; eA < e1A; eA += 4) {
            int s = col[eA];
            float w = dis[s] * dnA;
            f16x8 u = h8[(size_t)s * 16 + l4];
#pragma unroll
            for (int j = 0; j < 8; j++) aA[j] += (float)u[j] * w;
        }
        // drain B
        for (; eB + 12 < e1B; eB += 16) {
            int s0 = col[eB], s1 = col[eB + 4], s2 = col[eB + 8], s3 = col[eB + 12];
            float w0 = dis[s0], w1 = dis[s1], w2 = dis[s2], w3 = dis[s3];
            f16x8 u0 = h8[(size_t)s0 * 16 + l4];
            f16x8 u1 = h8[(size_t)s1 * 16 + l4];
            f16x8 u2 = h8[(size_t)s2 * 16 + l4];
            f16x8 u3 = h8[(size_t)s3 * 16 + l4];
            w0 *= dnB; w1 *= dnB; w2 *= dnB; w3 *= dnB;
#pragma unroll
            for (int j = 0; j < 8; j++) {
                aB[j] += (float)u0[j] * w0;
                aB[j] += (float)u1[j] * w1;
                aB[j] += (float)u2[j] * w2;
                aB[j] += (float)u3[j] * w3;
            }
        }
        for (; eB < e1B; eB += 4) {
            int s = col[eB];
            float w = dis[s] * dnB;
            f16x8 u = h8[(size_t)s * 16 + l4];
#pragma unroll
            for (int j = 0; j < 8; j++) aB[j] += (float)u[j] * w;
        }

        // combine the 4 edge-slot quarters for both nodes
#pragma unroll
        for (int j = 0; j < 8; j++) {
            aA[j] += __shfl_xor(aA[j], 16, 64);
            aA[j] += __shfl_xor(aA[j], 32, 64);
            aB[j] += __shfl_xor(aB[j], 16, 64);
            aB[j] += __shfl_xor(aB[j], 32, 64);
        }
        if (q == 0) {
            f16x8 oA, oB;
#pragma unroll
            for (int j = 0; j < 8; j++) { oA[j] = (_Float16)aA[j]; oB[j] = (_Float16)aB[j]; }
            *(f16x8*)&Ls[wave][i][l4 * 8] = oA;
            *(f16x8*)&Ls[wave][i + 1][l4 * 8] = oB;
        }
    }

    // ---- phase 2: read A-fragments into registers, then GEMM + LN (Ls reused) ----
    f16x8 af[4];
#pragma unroll
    for (int ks = 0; ks < 4; ks++)
        af[ks] = *(const f16x8*)&Ls[wave][l4][ks * 32 + q * 8];

    float bb[8], gm[8], bt[8];
#pragma unroll
    for (int nt = 0; nt < 8; nt++) {
        bb[nt] = bias[nt * 16 + l4];
        gm[nt] = gamma[nt * 16 + l4];
        bt[nt] = beta[nt * 16 + l4];
    }

    const f16x8* wp8 = (const f16x8*)Wp;
    f32x4 acc[8];
#pragma unroll
    for (int nt = 0; nt < 8; nt++) {
        acc[nt] = (f32x4){0.f, 0.f, 0.f, 0.f};
#pragma unroll
        for (int ks = 0; ks < 4; ks++) {
            f16x8 bf = wp8[(ks * 8 + nt) * 64 + lane];
            acc[nt] = __builtin_amdgcn_mfma_f32_16x16x32_f16(af[ks], bf, acc[nt], 0, 0, 0);
        }
#pragma unroll
        for (int r = 0; r < 4; r++) acc[nt][r] += bb[nt];
    }

    float mu[4], rs[4];
#pragma unroll
    for (int r = 0; r < 4; r++) {
        float s = 0.f;
#pragma unroll
        for (int nt = 0; nt < 8; nt++) s += acc[nt][r];
#pragma unroll
        for (int off = 8; off > 0; off >>= 1) s += __shfl_xor(s, off, 64);
        mu[r] = s * (1.f / 128.f);
    }
#pragma unroll
    for (int r = 0; r < 4; r++) {
        float v = 0.f;
#pragma unroll
        for (int nt = 0; nt < 8; nt++) {
            float d = acc[nt][r] - mu[r];
            v += d * d;
        }
#pragma unroll
        for (int off = 8; off > 0; off >>= 1) v += __shfl_xor(v, off, 64);
        rs[r] = rsqrtf(v * (1.f / 128.f) + EPS);
    }

    // overwrite Ls with LN output (af already in registers)
#pragma unroll
    for (int nt = 0; nt < 8; nt++)
#pragma unroll
        for (int r = 0; r < 4; r++) {
            float o = fmaxf((acc[nt][r] - mu[r]) * rs[r] * gm[nt] + bt[nt], 0.f);
            Ls[wave][q * 4 + r][nt * 16 + l4] = (_Float16)o;
        }

    // epilogue: residual add (hin) + coalesced store to hout
    const f16x8* hi8 = (const f16x8*)hin;
    f16x8* ho8 = (f16x8*)hout;
#pragma unroll
    for (int it = 0; it < 4; it++) {
        int c = it * 64 + lane;
        int rr = c >> 4, ck = c & 15;
        int row = nbase + rr;
        if (row < NN) {
            f16x8 ln = *(const f16x8*)&Ls[wave][rr][ck * 8];
            f16x8 res = hi8[(size_t)row * 16 + ck];
            f16x8 o;
#pragma unroll
            for (int j = 0; j < 8; j++) o[j] = (_Float16)((float)ln[j] + (float)res[j]);
            ho8[(size_t)row * 16 + ck] = o;
        }
    }
}

// ---------------- pooling ----------------

__global__ void k_range(const int* __restrict__ batch, int* __restrict__ gstart, int* __restrict__ gend) {
    int n = blockIdx.x * 256 + threadIdx.x;
    if (n < NN) {
        int g = batch[n];
        atomicMin(&gstart[g], n);
        atomicMax(&gend[g], n + 1);
    }
}

// One wave per graph; lane = (node slot p4, col group l4); f16x8 loads, 4 nodes/iter.
__global__ __launch_bounds__(256) void k_pool(const _Float16* __restrict__ hh, const int* __restrict__ gstart,
                                              const int* __restrict__ gend, const float* __restrict__ Wout,
                                              const float* __restrict__ bout, float* __restrict__ out) {
    int tid = threadIdx.x;
    int lane = tid & 63;
    int p4 = lane >> 4;     // node slot 0..3
    int l4 = lane & 15;     // cols l4*8 .. +7
    int g = blockIdx.x * 4 + (tid >> 6);
    if (g >= NG) return;

    int s = gstart[g], e = gend[g];
    const f16x8* h8 = (const f16x8*)hh;
    float acc[8];
#pragma unroll
    for (int j = 0; j < 8; j++) acc[j] = 0.f;
    for (int n = s + p4; n < e; n += 4) {
        f16x8 v = h8[(size_t)n * 16 + l4];
#pragma unroll
        for (int j = 0; j < 8; j++) acc[j] += (float)v[j];
    }
    // combine node slots
#pragma unroll
    for (int j = 0; j < 8; j++) {
        acc[j] += __shfl_xor(acc[j], 16, 64);
        acc[j] += __shfl_xor(acc[j], 32, 64);
    }
    float p = 0.f;
#pragma unroll
    for (int j = 0; j < 8; j++) p += acc[j] * Wout[l4 * 8 + j];
    // reduce across the 16 col groups
#pragma unroll
    for (int off = 8; off > 0; off >>= 1) p += __shfl_xor(p, off, 64);
    if (lane == 0) {
        float inv = 1.f / (float)max(e - s, 1);
        out[g] = p * inv + bout[0];
    }
}

// ---------------- launcher ----------------

extern "C" void kernel_launch(void* const* d_in, const int* in_sizes, int n_in,
                              void* d_out, int out_size, void* d_ws, size_t ws_size,
                              hipStream_t stream) {
    const float* x       = (const float*)d_in[0];
    const int*   edge    = (const int*)d_in[1];
    const int*   batch   = (const int*)d_in[2];
    const float* W_embed = (const float*)d_in[3];
    const float* b_embed = (const float*)d_in[4];
    const float* W_gnn   = (const float*)d_in[5];
    const float* b_gnn   = (const float*)d_in[6];
    const float* gamma   = (const float*)d_in[7];
    const float* beta    = (const float*)d_in[8];
    const float* W_out   = (const float*)d_in[9];
    const float* b_out   = (const float*)d_in[10];
    float* out = (float*)d_out;

    char* ws = (char*)d_ws;
    size_t off = 0;
    auto alloc = [&](size_t bytes) -> char* {
        char* p = ws + off;
        off += (bytes + 255) & ~(size_t)255;
        return p;
    };
    _Float16*     hh0  = (_Float16*)alloc((size_t)NN * H * 2);
    _Float16*     hh1  = (_Float16*)alloc((size_t)NN * H * 2);
    _Float16*     Wp   = (_Float16*)alloc((size_t)NL * 4 * 8 * 512 * 2);
    float*        dis  = (float*)alloc((size_t)NN * 4);
    int*          rps  = (int*)alloc((size_t)NN * 4);
    int*          rpe  = (int*)alloc((size_t)NN * 4);
    int*          col  = (int*)alloc((size_t)NBKT * CAP * 4);
    unsigned int* ebuf = (unsigned int*)alloc((size_t)NBKT * CAP * 4);
    int*          bfill = (int*)alloc((NBKT + 1) * 4);
    int*   gstart = (int*)alloc((size_t)NG * 4);
    int*   gend   = (int*)alloc((size_t)NG * 4);

    const int* srcp = edge;
    const int* dstp = edge + NE;

    k_init<<<(NG + 255) / 256, 256, 0, stream>>>(bfill, gstart, gend);
    k_bscatter<<<NBB, 256, 0, stream>>>(srcp, dstp, bfill, ebuf);
    k_bcsr<<<NBKT, 256, 0, stream>>>(ebuf, bfill, rps, rpe, col, dis);

    k_wpack<<<32, 256, 0, stream>>>(W_gnn, Wp);
    k_embed<<<NN / 16, 256, 0, stream>>>(x, W_embed, b_embed, hh0);

    // ping-pong: L0 hh0->hh1, L1 hh1->hh0, L2 hh0->hh1, L3 hh1->hh0
    _Float16* hb[2] = {hh0, hh1};
    for (int l = 0; l < NL; l++) {
        k_layer<<<(NN + 31) / 32, 128, 0, stream>>>(hb[l & 1], hb[(l & 1) ^ 1],
                                                    dis, rps, rpe, col,
                                                    Wp + (size_t)l * 4 * 8 * 512,
                                                    b_gnn + l * H, gamma + l * H, beta + l * H);
    }

    k_range<<<(NN + 255) / 256, 256, 0, stream>>>(batch, gstart, gend);
    k_pool<<<NG / 4, 256, 0, stream>>>(hh0, gstart, gend, W_out, b_out, out);
}

// Round 15
// 486.700 us; speedup vs baseline: 1.5116x; 1.5116x over previous
//
#include <hip/hip_runtime.h>

#define NN 100000
#define NE 1600000
#define DIM0 11
#define H 128
#define NL 4
#define NG 4096
#define EPS 1e-5f

#define NBKT 391       // buckets of 256 nodes: bucket = dst >> 8
#define CAP 5120       // fixed bucket capacity (mean 4096, sigma 64 -> 16 sigma)
#define EPB 4096       // edges per block in scatter phase
static constexpr int NBB = (NE + EPB - 1) / EPB;  // 391

typedef _Float16 f16x8 __attribute__((ext_vector_type(8)));
typedef _Float16 f16x2 __attribute__((ext_vector_type(2)));
typedef float f32x4 __attribute__((ext_vector_type(4)));

// r14 lesson: 2-node interleave in phase 1 doubled register demand -> scratch
// spill (WRITE 34->159MB) -> 154us. r13's single-node engine (VGPR 32, no
// spill) is the register-feasible shape; restored here. k_pool keeps the r14
// f16x8 4-node/iter layout (clean orthogonal win, different dispatch).

// ---------------- init ----------------

__global__ void k_init(int* __restrict__ bfill, int* __restrict__ gstart, int* __restrict__ gend) {
    int i = blockIdx.x * 256 + threadIdx.x;
    if (i <= NBKT) bfill[i] = 0;
    if (i < NG) { gstart[i] = 0x7fffffff; gend[i] = 0; }
}

// ---------------- bucketed CSR build ----------------

__global__ __launch_bounds__(256) void k_bscatter(const int* __restrict__ src, const int* __restrict__ dst,
                                                  int* __restrict__ bfill, unsigned int* __restrict__ ebuf) {
    __shared__ int lc[NBKT];
    __shared__ int lbase[NBKT];
    int t = threadIdx.x;
    for (int i = t; i < NBKT; i += 256) lc[i] = 0;
    __syncthreads();
    int base = blockIdx.x * EPB;
    int rank[16];
    int bk[16];
    unsigned pk[16];
#pragma unroll
    for (int i = 0; i < 16; i++) {
        int e = base + i * 256 + t;
        if (e < NE) {
            int d = dst[e];
            int s = src[e];
            int b = d >> 8;
            bk[i] = b;
            pk[i] = (unsigned)s | ((unsigned)(d & 255) << 17);
            rank[i] = atomicAdd(&lc[b], 1);
        } else bk[i] = -1;
    }
    __syncthreads();
    for (int i = t; i < NBKT; i += 256)
        lbase[i] = i * CAP + (lc[i] ? atomicAdd(&bfill[i], lc[i]) : 0);
    __syncthreads();
#pragma unroll
    for (int i = 0; i < 16; i++) {
        if (bk[i] >= 0)
            ebuf[lbase[bk[i]] + rank[i]] = pk[i];
    }
}

// One block per bucket (391 blocks): count -> dis, scan -> rps/rpe, scatter -> col.
__global__ __launch_bounds__(256) void k_bcsr(const unsigned int* __restrict__ ebuf,
                                              const int* __restrict__ bfill,
                                              int* __restrict__ rps, int* __restrict__ rpe,
                                              int* __restrict__ col, float* __restrict__ dis) {
    __shared__ int lcnt[256];
    __shared__ int lfill[256];
    __shared__ int tmp[256];
    int t = threadIdx.x;
    int b = blockIdx.x;
    int cb = b * CAP;
    int ecnt = bfill[b];
    int n0 = b << 8;
    int nb = min(256, NN - n0);

    lcnt[t] = 0;
    lfill[t] = 0;
    __syncthreads();

    for (int i = t; i < ecnt; i += 256) {
        unsigned p = ebuf[cb + i];
        atomicAdd(&lcnt[p >> 17], 1);
    }
    __syncthreads();

    if (t < nb) dis[n0 + t] = rsqrtf((float)(lcnt[t] + 1));

    int v = lcnt[t];
    tmp[t] = v;
    __syncthreads();
    for (int off = 1; off < 256; off <<= 1) {
        int x = (t >= off) ? tmp[t - off] : 0;
        __syncthreads();
        tmp[t] += x;
        __syncthreads();
    }
    lcnt[t] = tmp[t] - v;   // exclusive scan
    __syncthreads();

    if (t < nb) {
        rps[n0 + t] = cb + lcnt[t];
        rpe[n0 + t] = cb + ((t < 255) ? lcnt[t + 1] : ecnt);
    }

    for (int i = t; i < ecnt; i += 256) {
        unsigned p = ebuf[cb + i];
        int dl = p >> 17;
        int s = (int)(p & 0x1FFFFu);
        col[cb + lcnt[dl] + atomicAdd(&lfill[dl], 1)] = s;
    }
}

// ---------------- embed: hh = fp16(relu(x @ W_embed + b)), row-major ----------------

__global__ __launch_bounds__(256) void k_embed(const float* __restrict__ x, const float* __restrict__ W,
                                               const float* __restrict__ b, _Float16* __restrict__ hh) {
    __shared__ float Ws[DIM0 * H];
    __shared__ float bs[H];
    __shared__ float xs[16 * DIM0];
    int tid = threadIdx.x;
    for (int i = tid; i < DIM0 * H; i += 256) Ws[i] = W[i];
    if (tid < H) bs[tid] = b[tid];
    if (tid < 16 * DIM0) xs[tid] = x[(size_t)blockIdx.x * (16 * DIM0) + tid];
    __syncthreads();
    int nl = tid >> 4;
    int node = blockIdx.x * 16 + nl;
    int l4 = tid & 15;
    f16x8 o;
#pragma unroll
    for (int j = 0; j < 8; j++) {
        int c = l4 * 8 + j;
        float acc = bs[c];
#pragma unroll
        for (int k = 0; k < DIM0; k++) acc += xs[nl * DIM0 + k] * Ws[k * H + c];
        o[j] = (_Float16)fmaxf(acc, 0.f);
    }
    *(f16x8*)&hh[(size_t)node * H + l4 * 8] = o;
}

// ---------------- W pack: W[l][k][n] fp32 -> B-fragment-layout fp16 ----------------

__global__ __launch_bounds__(256) void k_wpack(const float* __restrict__ W, _Float16* __restrict__ Wp) {
    int t = blockIdx.x * 256 + threadIdx.x;   // 8192 threads
    int lane = t & 63;
    int idx = t >> 6;          // 0..127
    int nt = idx & 7;
    int ks = (idx >> 3) & 3;
    int l = idx >> 5;
    int q = lane >> 4, l15 = lane & 15;
    const float* Wl = W + (size_t)l * H * H;
    _Float16* o = Wp + (size_t)idx * 512 + lane * 8;
#pragma unroll
    for (int j = 0; j < 8; j++)
        o[j] = (_Float16)(Wl[(ks * 32 + q * 8 + j) * H + nt * 16 + l15]);
}

// ---------------- fused layer: hout = relu(LN(agg(hin) @ W + b)) + hin ----------------
// Block = 32 nodes, 2 waves (128 thr); wave-private 4.25KB LDS tile aliased
// between phase-1 agg rows and LN output. No __syncthreads anywhere.
// r13 shape: VGPR 32, no spill, ~85us at the gather fabric ceiling.

__global__ __launch_bounds__(128, 8) void k_layer(const _Float16* __restrict__ hin,
                                                  _Float16* __restrict__ hout,
                                                  const float* __restrict__ dis, const int* __restrict__ rps,
                                                  const int* __restrict__ rpe, const int* __restrict__ col,
                                                  const _Float16* __restrict__ Wp,
                                                  const float* __restrict__ bias,
                                                  const float* __restrict__ gamma,
                                                  const float* __restrict__ beta) {
    __shared__ _Float16 Ls[2][16][136];   // 8704 B
    int tid = threadIdx.x;
    int wave = tid >> 6;
    int lane = tid & 63;
    int q = lane >> 4, l4 = lane & 15;
    int nbase = blockIdx.x * 32 + wave * 16;

    const f16x8* h8 = (const f16x8*)hin;

    // ---- phase 1: gather 16 nodes into Ls ----
#pragma unroll 1
    for (int i = 0; i < 16; i++) {
        int node = __builtin_amdgcn_readfirstlane(nbase + i);
        float a[8];
#pragma unroll
        for (int j = 0; j < 8; j++) a[j] = 0.f;
        if (node < NN) {
            float dn = dis[node];
            if (q == 0) {  // self-loop counted once
                f16x8 sv = h8[(size_t)node * 16 + l4];
                float ws = dn * dn;
#pragma unroll
                for (int j = 0; j < 8; j++) a[j] = (float)sv[j] * ws;
            }
            int e0 = rps[node], e1 = rpe[node];
            int e = e0 + q;
            for (; e + 12 < e1; e += 16) {
                int s0 = col[e];
                int s1 = col[e + 4];
                int s2 = col[e + 8];
                int s3 = col[e + 12];
                float w0 = dis[s0];
                float w1 = dis[s1];
                float w2 = dis[s2];
                float w3 = dis[s3];
                f16x8 v0 = h8[(size_t)s0 * 16 + l4];
                f16x8 v1 = h8[(size_t)s1 * 16 + l4];
                f16x8 v2 = h8[(size_t)s2 * 16 + l4];
                f16x8 v3 = h8[(size_t)s3 * 16 + l4];
                w0 *= dn; w1 *= dn; w2 *= dn; w3 *= dn;
#pragma unroll
                for (int j = 0; j < 8; j++) {
                    a[j] += (float)v0[j] * w0;
                    a[j] += (float)v1[j] * w1;
                    a[j] += (float)v2[j] * w2;
                    a[j] += (float)v3[j] * w3;
                }
            }
            for (; e < e1; e += 4) {
                int s = col[e];
                float w = dis[s] * dn;
                f16x8 v = h8[(size_t)s * 16 + l4];
#pragma unroll
                for (int j = 0; j < 8; j++) a[j] += (float)v[j] * w;
            }
        }
        // combine the 4 edge-slot quarters
#pragma unroll
        for (int j = 0; j < 8; j++) {
            a[j] += __shfl_xor(a[j], 16, 64);
            a[j] += __shfl_xor(a[j], 32, 64);
        }
        if (q == 0) {
            f16x8 o;
#pragma unroll
            for (int j = 0; j < 8; j++) o[j] = (_Float16)a[j];
            *(f16x8*)&Ls[wave][i][l4 * 8] = o;
        }
    }

    // ---- phase 2: read A-fragments into registers, then GEMM + LN (Ls reused) ----
    f16x8 af[4];
#pragma unroll
    for (int ks = 0; ks < 4; ks++)
        af[ks] = *(const f16x8*)&Ls[wave][l4][ks * 32 + q * 8];

    float bb[8], gm[8], bt[8];
#pragma unroll
    for (int nt = 0; nt < 8; nt++) {
        bb[nt] = bias[nt * 16 + l4];
        gm[nt] = gamma[nt * 16 + l4];
        bt[nt] = beta[nt * 16 + l4];
    }

    const f16x8* wp8 = (const f16x8*)Wp;
    f32x4 acc[8];
#pragma unroll
    for (int nt = 0; nt < 8; nt++) {
        acc[nt] = (f32x4){0.f, 0.f, 0.f, 0.f};
#pragma unroll
        for (int ks = 0; ks < 4; ks++) {
            f16x8 bf = wp8[(ks * 8 + nt) * 64 + lane];
            acc[nt] = __builtin_amdgcn_mfma_f32_16x16x32_f16(af[ks], bf, acc[nt], 0, 0, 0);
        }
#pragma unroll
        for (int r = 0; r < 4; r++) acc[nt][r] += bb[nt];
    }

    float mu[4], rs[4];
#pragma unroll
    for (int r = 0; r < 4; r++) {
        float s = 0.f;
#pragma unroll
        for (int nt = 0; nt < 8; nt++) s += acc[nt][r];
#pragma unroll
        for (int off = 8; off > 0; off >>= 1) s += __shfl_xor(s, off, 64);
        mu[r] = s * (1.f / 128.f);
    }
#pragma unroll
    for (int r = 0; r < 4; r++) {
        float v = 0.f;
#pragma unroll
        for (int nt = 0; nt < 8; nt++) {
            float d = acc[nt][r] - mu[r];
            v += d * d;
        }
#pragma unroll
        for (int off = 8; off > 0; off >>= 1) v += __shfl_xor(v, off, 64);
        rs[r] = rsqrtf(v * (1.f / 128.f) + EPS);
    }

    // overwrite Ls with LN output (af already in registers)
#pragma unroll
    for (int nt = 0; nt < 8; nt++)
#pragma unroll
        for (int r = 0; r < 4; r++) {
            float o = fmaxf((acc[nt][r] - mu[r]) * rs[r] * gm[nt] + bt[nt], 0.f);
            Ls[wave][q * 4 + r][nt * 16 + l4] = (_Float16)o;
        }

    // epilogue: residual add (hin) + coalesced store to hout
    const f16x8* hi8 = (const f16x8*)hin;
    f16x8* ho8 = (f16x8*)hout;
#pragma unroll
    for (int it = 0; it < 4; it++) {
        int c = it * 64 + lane;
        int rr = c >> 4, ck = c & 15;
        int row = nbase + rr;
        if (row < NN) {
            f16x8 ln = *(const f16x8*)&Ls[wave][rr][ck * 8];
            f16x8 res = hi8[(size_t)row * 16 + ck];
            f16x8 o;
#pragma unroll
            for (int j = 0; j < 8; j++) o[j] = (_Float16)((float)ln[j] + (float)res[j]);
            ho8[(size_t)row * 16 + ck] = o;
        }
    }
}

// ---------------- pooling ----------------

__global__ void k_range(const int* __restrict__ batch, int* __restrict__ gstart, int* __restrict__ gend) {
    int n = blockIdx.x * 256 + threadIdx.x;
    if (n < NN) {
        int g = batch[n];
        atomicMin(&gstart[g], n);
        atomicMax(&gend[g], n + 1);
    }
}

// One wave per graph; lane = (node slot p4, col group l4); f16x8 loads, 4 nodes/iter.
__global__ __launch_bounds__(256) void k_pool(const _Float16* __restrict__ hh, const int* __restrict__ gstart,
                                              const int* __restrict__ gend, const float* __restrict__ Wout,
                                              const float* __restrict__ bout, float* __restrict__ out) {
    int tid = threadIdx.x;
    int lane = tid & 63;
    int p4 = lane >> 4;     // node slot 0..3
    int l4 = lane & 15;     // cols l4*8 .. +7
    int g = blockIdx.x * 4 + (tid >> 6);
    if (g >= NG) return;

    int s = gstart[g], e = gend[g];
    const f16x8* h8 = (const f16x8*)hh;
    float acc[8];
#pragma unroll
    for (int j = 0; j < 8; j++) acc[j] = 0.f;
    for (int n = s + p4; n < e; n += 4) {
        f16x8 v = h8[(size_t)n * 16 + l4];
#pragma unroll
        for (int j = 0; j < 8; j++) acc[j] += (float)v[j];
    }
    // combine node slots
#pragma unroll
    for (int j = 0; j < 8; j++) {
        acc[j] += __shfl_xor(acc[j], 16, 64);
        acc[j] += __shfl_xor(acc[j], 32, 64);
    }
    float p = 0.f;
#pragma unroll
    for (int j = 0; j < 8; j++) p += acc[j] * Wout[l4 * 8 + j];
    // reduce across the 16 col groups
#pragma unroll
    for (int off = 8; off > 0; off >>= 1) p += __shfl_xor(p, off, 64);
    if (lane == 0) {
        float inv = 1.f / (float)max(e - s, 1);
        out[g] = p * inv + bout[0];
    }
}

// ---------------- launcher ----------------

extern "C" void kernel_launch(void* const* d_in, const int* in_sizes, int n_in,
                              void* d_out, int out_size, void* d_ws, size_t ws_size,
                              hipStream_t stream) {
    const float* x       = (const float*)d_in[0];
    const int*   edge    = (const int*)d_in[1];
    const int*   batch   = (const int*)d_in[2];
    const float* W_embed = (const float*)d_in[3];
    const float* b_embed = (const float*)d_in[4];
    const float* W_gnn   = (const float*)d_in[5];
    const float* b_gnn   = (const float*)d_in[6];
    const float* gamma   = (const float*)d_in[7];
    const float* beta    = (const float*)d_in[8];
    const float* W_out   = (const float*)d_in[9];
    const float* b_out   = (const float*)d_in[10];
    float* out = (float*)d_out;

    char* ws = (char*)d_ws;
    size_t off = 0;
    auto alloc = [&](size_t bytes) -> char* {
        char* p = ws + off;
        off += (bytes + 255) & ~(size_t)255;
        return p;
    };
    _Float16*     hh0  = (_Float16*)alloc((size_t)NN * H * 2);
    _Float16*     hh1  = (_Float16*)alloc((size_t)NN * H * 2);
    _Float16*     Wp   = (_Float16*)alloc((size_t)NL * 4 * 8 * 512 * 2);
    float*        dis  = (float*)alloc((size_t)NN * 4);
    int*          rps  = (int*)alloc((size_t)NN * 4);
    int*          rpe  = (int*)alloc((size_t)NN * 4);
    int*          col  = (int*)alloc((size_t)NBKT * CAP * 4);
    unsigned int* ebuf = (unsigned int*)alloc((size_t)NBKT * CAP * 4);
    int*          bfill = (int*)alloc((NBKT + 1) * 4);
    int*   gstart = (int*)alloc((size_t)NG * 4);
    int*   gend   = (int*)alloc((size_t)NG * 4);

    const int* srcp = edge;
    const int* dstp = edge + NE;

    k_init<<<(NG + 255) / 256, 256, 0, stream>>>(bfill, gstart, gend);
    k_bscatter<<<NBB, 256, 0, stream>>>(srcp, dstp, bfill, ebuf);
    k_bcsr<<<NBKT, 256, 0, stream>>>(ebuf, bfill, rps, rpe, col, dis);

    k_wpack<<<32, 256, 0, stream>>>(W_gnn, Wp);
    k_embed<<<NN / 16, 256, 0, stream>>>(x, W_embed, b_embed, hh0);

    // ping-pong: L0 hh0->hh1, L1 hh1->hh0, L2 hh0->hh1, L3 hh1->hh0
    _Float16* hb[2] = {hh0, hh1};
    for (int l = 0; l < NL; l++) {
        k_layer<<<(NN + 31) / 32, 128, 0, stream>>>(hb[l & 1], hb[(l & 1) ^ 1],
                                                    dis, rps, rpe, col,
                                                    Wp + (size_t)l * 4 * 8 * 512,
                                                    b_gnn + l * H, gamma + l * H, beta + l * H);
    }

    k_range<<<(NN + 255) / 256, 256, 0, stream>>>(batch, gstart, gend);
    k_pool<<<NG / 4, 256, 0, stream>>>(hh0, gstart, gend, W_out, b_out, out);
}